// Round 1
// baseline (235.104 us; speedup 1.0000x reference)
//
#include <hip/hip_runtime.h>

// 8x8 block IDCT with dequantization:
// out[b,0,R,C] = sum_{j,k} mtx[j][R%8] * x[b,0,(R/8)*8+j,(C/8)*8+k] * qt[j][k] * mtx[k][C%8] + 128
// One thread per 8x8 block, block held fully in registers.
// B=32, H=W=1024 -> 524288 blocks -> grid 2048 x 256 threads.

__global__ __launch_bounds__(256) void bidct_kernel(
    const float* __restrict__ x, const float* __restrict__ qt,
    const float* __restrict__ mtx, float* __restrict__ out)
{
    __shared__ float sM[64];
    __shared__ float sQ[64];
    const int t = threadIdx.x;
    if (t < 64) { sM[t] = mtx[t]; sQ[t] = qt[t]; }
    __syncthreads();

    const int n = blockIdx.x * 256 + t;            // global 8x8-block index
    // flat element base of this block: (n>>7)*8192 + (n&127)*8
    const int base = ((n >> 7) << 13) + ((n & 127) << 3);

    // Load the 8x8 tile (two float4 per row), dequantize.
    float X[8][8];
#pragma unroll
    for (int j = 0; j < 8; ++j) {
        const float4* p = reinterpret_cast<const float4*>(x + base + j * 1024);
        float4 a = p[0];
        float4 b = p[1];
        X[j][0] = a.x; X[j][1] = a.y; X[j][2] = a.z; X[j][3] = a.w;
        X[j][4] = b.x; X[j][5] = b.y; X[j][6] = b.z; X[j][7] = b.w;
    }
#pragma unroll
    for (int j = 0; j < 8; ++j)
#pragma unroll
        for (int k = 0; k < 8; ++k)
            X[j][k] *= sQ[j * 8 + k];

    // T = M^T * Xq   (T[i][k] = sum_j M[j][i] * Xq[j][k])
    float T[8][8];
#pragma unroll
    for (int i = 0; i < 8; ++i) {
#pragma unroll
        for (int k = 0; k < 8; ++k) {
            float acc = 0.0f;
#pragma unroll
            for (int j = 0; j < 8; ++j)
                acc += sM[j * 8 + i] * X[j][k];
            T[i][k] = acc;
        }
    }

    // out_row[i][l] = sum_k T[i][k] * M[k][l] + 128, stored row by row.
#pragma unroll
    for (int i = 0; i < 8; ++i) {
        float o[8];
#pragma unroll
        for (int l = 0; l < 8; ++l) {
            float acc = 128.0f;
#pragma unroll
            for (int k = 0; k < 8; ++k)
                acc += T[i][k] * sM[k * 8 + l];
            o[l] = acc;
        }
        float4* q = reinterpret_cast<float4*>(out + base + i * 1024);
        q[0] = make_float4(o[0], o[1], o[2], o[3]);
        q[1] = make_float4(o[4], o[5], o[6], o[7]);
    }
}

extern "C" void kernel_launch(void* const* d_in, const int* in_sizes, int n_in,
                              void* d_out, int out_size, void* d_ws, size_t ws_size,
                              hipStream_t stream) {
    const float* x    = (const float*)d_in[0];
    const float* qt   = (const float*)d_in[1];
    const float* mtx  = (const float*)d_in[2];
    float*       out  = (float*)d_out;

    const int total_blocks = out_size / 64;        // 524288 for 32x1x1024x1024
    const int grid = (total_blocks + 255) / 256;   // 2048
    bidct_kernel<<<grid, 256, 0, stream>>>(x, qt, mtx, out);
}

// Round 2
// 230.349 us; speedup vs baseline: 1.0206x; 1.0206x over previous
//
#include <hip/hip_runtime.h>

// Cooperative 8x8 block IDCT + dequant.
// Each 256-thread workgroup processes an 8-row x 256-col stripe = 32 blocks (8 KB).
// Phase 1: fully-coalesced float4 global->LDS load, dequant folded in.
// Phase 2: 8 threads per block; thread (blk, i) computes output row i:
//          T[k] = sum_j M[j][i] * Xq[j][k];  o[l] = 128 + sum_k T[k] * M[k][l]
// Phase 3: rows written back to LDS, then fully-coalesced float4 store.

__global__ __launch_bounds__(256, 8) void bidct_kernel(
    const float* __restrict__ x, const float* __restrict__ qt,
    const float* __restrict__ mtx, float* __restrict__ out)
{
    __shared__ float tile[2048];   // 8 rows x 256 cols
    __shared__ float sM[64];
    __shared__ float sQ[64];

    const int t = threadIdx.x;
    if (t < 64) { sM[t] = mtx[t]; sQ[t] = qt[t]; }
    __syncthreads();

    const int w = blockIdx.x;
    // stripe base: row-group (w>>2) of 8 rows, col offset (w&3)*256
    const int base = (w >> 2) * 8192 + (w & 3) * 256;

    float4* tile4 = reinterpret_cast<float4*>(tile);
    const float4* sM4 = reinterpret_cast<const float4*>(sM);

    // ---- Phase 1: coalesced load + dequantize ----
#pragma unroll
    for (int r = 0; r < 2; ++r) {
        const int f  = r * 256 + t;        // float4 index 0..511
        const int j  = f >> 6;             // row 0..7
        const int c4 = f & 63;             // float4-col 0..63
        float4 v = *reinterpret_cast<const float4*>(x + base + j * 1024 + c4 * 4);
        const int k0 = (c4 & 1) * 4;       // col within 8x8 block
        v.x *= sQ[j * 8 + k0 + 0];
        v.y *= sQ[j * 8 + k0 + 1];
        v.z *= sQ[j * 8 + k0 + 2];
        v.w *= sQ[j * 8 + k0 + 3];
        tile4[f] = v;                      // tile[j][c4*4..] (f == j*64 + c4)
    }
    __syncthreads();

    // ---- Phase 2: per-row IDCT ----
    const int bl = t >> 3;                 // block within stripe, 0..31
    const int i  = t & 7;                  // output row within block

    float T[8] = {0.f, 0.f, 0.f, 0.f, 0.f, 0.f, 0.f, 0.f};
#pragma unroll
    for (int j = 0; j < 8; ++j) {
        const float m = sM[j * 8 + i];
        const float4 xa = tile4[j * 64 + bl * 2];
        const float4 xb = tile4[j * 64 + bl * 2 + 1];
        T[0] = fmaf(m, xa.x, T[0]);
        T[1] = fmaf(m, xa.y, T[1]);
        T[2] = fmaf(m, xa.z, T[2]);
        T[3] = fmaf(m, xa.w, T[3]);
        T[4] = fmaf(m, xb.x, T[4]);
        T[5] = fmaf(m, xb.y, T[5]);
        T[6] = fmaf(m, xb.z, T[6]);
        T[7] = fmaf(m, xb.w, T[7]);
    }

    float o[8] = {128.f, 128.f, 128.f, 128.f, 128.f, 128.f, 128.f, 128.f};
#pragma unroll
    for (int k = 0; k < 8; ++k) {
        const float4 m0 = sM4[k * 2];      // M[k][0..3] (broadcast)
        const float4 m1 = sM4[k * 2 + 1];  // M[k][4..7]
        o[0] = fmaf(T[k], m0.x, o[0]);
        o[1] = fmaf(T[k], m0.y, o[1]);
        o[2] = fmaf(T[k], m0.z, o[2]);
        o[3] = fmaf(T[k], m0.w, o[3]);
        o[4] = fmaf(T[k], m1.x, o[4]);
        o[5] = fmaf(T[k], m1.y, o[5]);
        o[6] = fmaf(T[k], m1.z, o[6]);
        o[7] = fmaf(T[k], m1.w, o[7]);
    }
    __syncthreads();                       // everyone done reading tile

    tile4[i * 64 + bl * 2]     = make_float4(o[0], o[1], o[2], o[3]);
    tile4[i * 64 + bl * 2 + 1] = make_float4(o[4], o[5], o[6], o[7]);
    __syncthreads();

    // ---- Phase 3: coalesced store ----
#pragma unroll
    for (int r = 0; r < 2; ++r) {
        const int f  = r * 256 + t;
        const int j  = f >> 6;
        const int c4 = f & 63;
        *reinterpret_cast<float4*>(out + base + j * 1024 + c4 * 4) = tile4[f];
    }
}

extern "C" void kernel_launch(void* const* d_in, const int* in_sizes, int n_in,
                              void* d_out, int out_size, void* d_ws, size_t ws_size,
                              hipStream_t stream) {
    const float* x   = (const float*)d_in[0];
    const float* qt  = (const float*)d_in[1];
    const float* mtx = (const float*)d_in[2];
    float*       out = (float*)d_out;

    const int grid = out_size / 2048;      // 16384 workgroups of 256 threads
    bidct_kernel<<<grid, 256, 0, stream>>>(x, qt, mtx, out);
}